// Round 3
// baseline (87.638 us; speedup 1.0000x reference)
//
#include <hip/hip_runtime.h>
#include <hip/hip_bf16.h>
#include <cstdint>
#include <cstddef>

#define N_PTS 4096
#define DIM   2048
#define NT    32          // K-tiles of 64
#define NBT   16          // 4096 / 256 tile grid

typedef __bf16 bf16x8 __attribute__((ext_vector_type(8)));
typedef float  f32x4  __attribute__((ext_vector_type(4)));
typedef unsigned short u16x8 __attribute__((ext_vector_type(8)));

__device__ __forceinline__ unsigned short f32_to_bf16_rne(float f) {
  unsigned u = __float_as_uint(f);
  u += 0x7fffu + ((u >> 16) & 1u);
  return (unsigned short)(u >> 16);
}

__device__ __forceinline__ void load_lds16(const void* g, void* l) {
  __builtin_amdgcn_global_load_lds(
      (const __attribute__((address_space(1))) void*)g,
      (__attribute__((address_space(3))) void*)l, 16, 0, 0);
}

__device__ __forceinline__ void barrier_fence() {
  asm volatile("" ::: "memory");
  __builtin_amdgcn_s_barrier();
  asm volatile("" ::: "memory");
  __builtin_amdgcn_sched_barrier(0);
}

#define WAIT_VMCNT4() asm volatile("s_waitcnt vmcnt(4)" ::: "memory")

// ---------------- prep: fp32 -> bf16 + exact fp32 row sum-of-squares + init far/near ---
__global__ __launch_bounds__(256) void prep_kernel(const float* __restrict__ X,
                                                   unsigned short* __restrict__ Xb,
                                                   float* __restrict__ sq,
                                                   unsigned* __restrict__ far_bits,
                                                   unsigned* __restrict__ near_bits) {
  const int row = blockIdx.x;
  const int t = threadIdx.x;
  const float4* xr = (const float4*)(X + (size_t)row * DIM);
  float4 v0 = xr[t * 2 + 0];
  float4 v1 = xr[t * 2 + 1];
  float s = v0.x * v0.x + v0.y * v0.y + v0.z * v0.z + v0.w * v0.w
          + v1.x * v1.x + v1.y * v1.y + v1.z * v1.z + v1.w * v1.w;
  u16x8 o;
  o[0] = f32_to_bf16_rne(v0.x); o[1] = f32_to_bf16_rne(v0.y);
  o[2] = f32_to_bf16_rne(v0.z); o[3] = f32_to_bf16_rne(v0.w);
  o[4] = f32_to_bf16_rne(v1.x); o[5] = f32_to_bf16_rne(v1.y);
  o[6] = f32_to_bf16_rne(v1.z); o[7] = f32_to_bf16_rne(v1.w);
  *(u16x8*)(Xb + (size_t)row * DIM + t * 8) = o;

  #pragma unroll
  for (int off = 32; off > 0; off >>= 1) s += __shfl_down(s, off, 64);
  __shared__ float wsum[4];
  const int lane = t & 63, w = t >> 6;
  if (lane == 0) wsum[w] = s;
  __syncthreads();
  if (t == 0) {
    sq[row] = wsum[0] + wsum[1] + wsum[2] + wsum[3];
    far_bits[row]  = 0u;           // 0.0f
    near_bits[row] = 0x7f800000u;  // +inf
  }
}

// ---------------- 256x256 8-phase pairwise-dist kernel ----------------
// LDS map (bytes):
//   A slots: (db*2+h)*16384              for db,h in {0,1}   [0, 65536)
//   B slots: 65536 + (db*2+h)*16384                          [65536, 131072)
//   sq_r @131072, t_r @132096, sq_c @133120, t_c @134144 ; total 135168
// Each 16 KiB slot = 128 rows x 64 cols bf16, stored as 16 subtiles of
// 16x32 (1024 B); within subtile byte = r'*64 + (c' ^ ((r'>=8)?16:0))*2.
__device__ __forceinline__ void read8(bf16x8 (&f)[4][2], const char* base) {
  #pragma unroll
  for (int m = 0; m < 4; ++m)
    #pragma unroll
    for (int kh = 0; kh < 2; ++kh)
      f[m][kh] = *(const bf16x8*)(base + ((m * 2 + kh) << 10));
}
__device__ __forceinline__ void read4(bf16x8 (&f)[2][2], const char* base) {
  #pragma unroll
  for (int n = 0; n < 2; ++n)
    #pragma unroll
    for (int kh = 0; kh < 2; ++kh)
      f[n][kh] = *(const bf16x8*)(base + ((n * 2 + kh) << 10));
}

template<int MB, int NBq>
__device__ __forceinline__ void do_mfma(f32x4 (&acc)[8][4], bf16x8 (&af)[4][2], bf16x8 (&bf)[2][2]) {
  __builtin_amdgcn_s_setprio(1);
  #pragma unroll
  for (int m = 0; m < 4; ++m)
    #pragma unroll
    for (int n = 0; n < 2; ++n)
      #pragma unroll
      for (int kh = 0; kh < 2; ++kh)
        acc[MB * 4 + m][NBq * 2 + n] =
            __builtin_amdgcn_mfma_f32_16x16x32_bf16(af[m][kh], bf[n][kh],
                                                    acc[MB * 4 + m][NBq * 2 + n], 0, 0, 0);
  __builtin_amdgcn_s_setprio(0);
}

__global__ __launch_bounds__(512, 2) void pairdist_kernel(
    const unsigned short* __restrict__ Xb, const float* __restrict__ sq,
    const int* __restrict__ tgt, unsigned* __restrict__ far_bits,
    unsigned* __restrict__ near_bits) {
  __shared__ __align__(16) char sm[135168];

  const int tid  = threadIdx.x;
  const int lane = tid & 63;
  const int w    = tid >> 6;        // 0..7
  const int wr   = w >> 2;          // 0..1  (M)
  const int wcn  = w & 3;           // 0..3  (N)
  const int fr   = lane & 15;
  const int hi4  = lane >> 4;
  const int i0   = blockIdx.y * 256;
  const int j0   = blockIdx.x * 256;

  float* sq_r = (float*)(sm + 131072);
  int*   t_r  = (int*)  (sm + 132096);
  float* sq_c = (float*)(sm + 133120);
  int*   t_c  = (int*)  (sm + 134144);
  if (tid < 256) { sq_r[tid] = sq[i0 + tid]; t_r[tid] = tgt[i0 + tid]; }
  else { int c = tid - 256; sq_c[c] = sq[j0 + c]; t_c[c] = tgt[j0 + c]; }

  // ds_read per-lane byte offset within a subtile (swizzled)
  const int ard = fr * 64 + ((hi4 * 16) ^ ((lane & 8) << 2));
  const char* smA = sm + wr * 16384 + ard;                                  // +db*32768, +(m*2+kh)*1024
  const char* smB = sm + 65536 + (wcn >> 1) * 16384 + (wcn & 1) * 8192 + ard;

  // staging: per instr a wave covers one 1024-B subtile; lane l -> r'=l>>2,
  // global col pre-swizzled so linear LDS dest yields the swizzled layout.
  const int srow = lane >> 2;
  const int scol = ((lane & 3) * 8) ^ ((lane & 32) ? 16 : 0);
  const unsigned short* gA_src = Xb + (size_t)(i0 + w * 16 + srow) * DIM + scol;
  const unsigned short* gB_src = Xb + (size_t)(j0 + w * 16 + srow) * DIM + scol;
  const int wq0 = w * 2048, wq1 = w * 2048 + 1024;

#define STG_A(db, h, kt) do { \
    const unsigned short* s_ = gA_src + (size_t)(h) * 128 * DIM + (kt) * 64; \
    load_lds16(s_,      sm + ((db) * 2 + (h)) * 16384 + wq0); \
    load_lds16(s_ + 32, sm + ((db) * 2 + (h)) * 16384 + wq1); } while (0)
#define STG_B(db, h, kt) do { \
    const unsigned short* s_ = gB_src + (size_t)(h) * 128 * DIM + (kt) * 64; \
    load_lds16(s_,      sm + 65536 + ((db) * 2 + (h)) * 16384 + wq0); \
    load_lds16(s_ + 32, sm + 65536 + ((db) * 2 + (h)) * 16384 + wq1); } while (0)

  f32x4 acc[8][4] = {};
  bf16x8 a03f[4][2], a47f[4][2], b01f[2][2], b23f[2][2];

  // prologue: tile0 (db0) fully + B(1)h0, A(1)h0 (db1)
  STG_A(0, 0, 0); STG_A(0, 1, 0); STG_B(0, 0, 0); STG_B(0, 1, 0);
  STG_B(1, 0, 1); STG_A(1, 0, 1);
  asm volatile("s_waitcnt lgkmcnt(0)" ::: "memory");  // sq/t LDS writes
  WAIT_VMCNT4();
  barrier_fence();

  for (int it = 0; it < NT / 2; ++it) {
    const int t = 2 * it;
    // ph1: db0 reads a03+b01; stage B(t+1)h1; mfma m0-3 x n0-1
    read8(a03f, smA);
    read4(b01f, smB);
    STG_B(1, 1, t + 1);
    barrier_fence();
    do_mfma<0, 0>(acc, a03f, b01f);
    barrier_fence();
    // ph2: read b23; stage A(t+1)h1; mfma m0-3 x n2-3
    read4(b23f, smB + 4096);
    STG_A(1, 1, t + 1);
    barrier_fence();
    do_mfma<0, 1>(acc, a03f, b23f);
    barrier_fence();
    // ph3: read a47; stage B(t+2)h0; mfma m4-7 x n2-3
    read8(a47f, smA + 8192);
    if (t + 2 < NT) STG_B(0, 0, t + 2);
    barrier_fence();
    do_mfma<1, 1>(acc, a47f, b23f);
    barrier_fence();
    // ph4: stage A(t+2)h0; vmcnt(4); mfma m4-7 x n0-1
    if (t + 2 < NT) STG_A(0, 0, t + 2);
    WAIT_VMCNT4();
    barrier_fence();
    do_mfma<1, 0>(acc, a47f, b01f);
    barrier_fence();
    // ph5: db1 reads a03+b01; stage B(t+2)h1; mfma m0-3 x n0-1
    read8(a03f, smA + 32768);
    read4(b01f, smB + 32768);
    if (t + 2 < NT) STG_B(0, 1, t + 2);
    barrier_fence();
    do_mfma<0, 0>(acc, a03f, b01f);
    barrier_fence();
    // ph6: read b23; stage A(t+2)h1; mfma m0-3 x n2-3
    read4(b23f, smB + 32768 + 4096);
    if (t + 2 < NT) STG_A(0, 1, t + 2);
    barrier_fence();
    do_mfma<0, 1>(acc, a03f, b23f);
    barrier_fence();
    // ph7: read a47; stage B(t+3)h0; mfma m4-7 x n2-3
    read8(a47f, smA + 32768 + 8192);
    if (t + 3 < NT) STG_B(1, 0, t + 3);
    barrier_fence();
    do_mfma<1, 1>(acc, a47f, b23f);
    barrier_fence();
    // ph8: stage A(t+3)h0; vmcnt(4); mfma m4-7 x n0-1
    if (t + 3 < NT) STG_A(1, 0, t + 3);
    WAIT_VMCNT4();
    barrier_fence();
    do_mfma<1, 0>(acc, a47f, b01f);
    barrier_fence();
  }
#undef STG_A
#undef STG_B

  // ---- epilogue: d^2, masked row-side far/near, sqrt after reduce ----
  const float INF = __builtin_inff();
  #pragma unroll
  for (int m = 0; m < 8; ++m) {
    #pragma unroll
    for (int r = 0; r < 4; ++r) {
      const int rl = wr * 128 + m * 16 + hi4 * 4 + r;
      const int gi = i0 + rl;
      const float sqr = sq_r[rl];
      const int   trw = t_r[rl];
      float fmx = 0.0f;
      float nmn = INF;
      #pragma unroll
      for (int n = 0; n < 4; ++n) {
        const int cl = wcn * 64 + n * 16 + fr;
        const float d2 = fmaf(-2.0f, acc[m][n][r], sqr + sq_c[cl]);
        if (trw == t_c[cl]) {
          fmx = fmaxf(fmx, d2);
          if (gi != j0 + cl) nmn = fminf(nmn, d2);
        }
      }
      #pragma unroll
      for (int s = 1; s < 16; s <<= 1) {
        fmx = fmaxf(fmx, __shfl_xor(fmx, s, 64));
        nmn = fminf(nmn, __shfl_xor(nmn, s, 64));
      }
      if (fr == 0) {
        atomicMax(&far_bits[gi],  __float_as_uint(sqrtf(fmaxf(fmx, 1e-12f))));
        atomicMin(&near_bits[gi], __float_as_uint(sqrtf(fmaxf(nmn, 1e-12f))));
      }
    }
  }
}

// ---------------- final deterministic reduction ----------------
__global__ __launch_bounds__(256) void finalize_kernel(
    const unsigned* __restrict__ far_bits, const unsigned* __restrict__ near_bits,
    float* __restrict__ out) {
  __shared__ float red[256];
  const int t = threadIdx.x;
  float s = 0.0f;
  for (int i = t; i < N_PTS; i += 256) {
    float fa = __uint_as_float(far_bits[i]);
    float ne = __uint_as_float(near_bits[i]);
    s += fmaxf(fa - ne, 0.0f);   // near=+inf -> -inf -> 0
  }
  red[t] = s;
  __syncthreads();
  for (int off = 128; off > 0; off >>= 1) {
    if (t < off) red[t] += red[t + off];
    __syncthreads();
  }
  if (t == 0) out[0] = red[0] / (float)N_PTS;
}

extern "C" void kernel_launch(void* const* d_in, const int* in_sizes, int n_in,
                              void* d_out, int out_size, void* d_ws, size_t ws_size,
                              hipStream_t stream) {
  const float* X   = (const float*)d_in[0];
  const int*   tgt = (const int*)d_in[1];
  float*       out = (float*)d_out;

  char* ws = (char*)d_ws;
  unsigned short* Xb = (unsigned short*)ws;                       // 16 MiB
  float*    sq     = (float*)(ws + (size_t)N_PTS * DIM * 2);      // 16 KiB
  unsigned* far_b  = (unsigned*)(ws + (size_t)N_PTS * DIM * 2 + N_PTS * 4);
  unsigned* near_b = (unsigned*)(ws + (size_t)N_PTS * DIM * 2 + N_PTS * 8);

  prep_kernel<<<N_PTS, 256, 0, stream>>>(X, Xb, sq, far_b, near_b);
  dim3 grid(NBT, NBT);
  pairdist_kernel<<<grid, 512, 0, stream>>>(Xb, sq, tgt, far_b, near_b);
  finalize_kernel<<<1, 256, 0, stream>>>(far_b, near_b, out);
}

// Round 4
// 87.621 us; speedup vs baseline: 1.0002x; 1.0002x over previous
//
#include <hip/hip_runtime.h>
#include <hip/hip_bf16.h>
#include <cstdint>
#include <cstddef>

#define N_PTS 4096
#define DIM   2048
#define NT    32          // K-tiles of 64
#define NBT   16          // 4096 / 256 tile grid

typedef __bf16 bf16x8 __attribute__((ext_vector_type(8)));
typedef float  f32x4  __attribute__((ext_vector_type(4)));
typedef unsigned short u16x8 __attribute__((ext_vector_type(8)));

__device__ __forceinline__ unsigned short f32_to_bf16_rne(float f) {
  unsigned u = __float_as_uint(f);
  u += 0x7fffu + ((u >> 16) & 1u);
  return (unsigned short)(u >> 16);
}

__device__ __forceinline__ void load_lds16(const void* g, void* l) {
  __builtin_amdgcn_global_load_lds(
      (const __attribute__((address_space(1))) void*)g,
      (__attribute__((address_space(3))) void*)l, 16, 0, 0);
}

// Raw barrier — NO sched_barrier, NO memory clobber (m141/m201 lesson:
// pinning the scheduler costs ~1.7x; the verified 8-phase template uses
// plain s_barrier and lets the compiler schedule reads/MFMA/addr-calc).
#define BAR() __builtin_amdgcn_s_barrier()
#define WAIT_VMCNT4() asm volatile("s_waitcnt vmcnt(4)" ::: "memory")

// ---------------- prep: fp32 -> bf16 + exact fp32 row sum-of-squares + init far/near ---
__global__ __launch_bounds__(256) void prep_kernel(const float* __restrict__ X,
                                                   unsigned short* __restrict__ Xb,
                                                   float* __restrict__ sq,
                                                   unsigned* __restrict__ far_bits,
                                                   unsigned* __restrict__ near_bits) {
  const int row = blockIdx.x;
  const int t = threadIdx.x;
  const float4* xr = (const float4*)(X + (size_t)row * DIM);
  float4 v0 = xr[t * 2 + 0];
  float4 v1 = xr[t * 2 + 1];
  float s = v0.x * v0.x + v0.y * v0.y + v0.z * v0.z + v0.w * v0.w
          + v1.x * v1.x + v1.y * v1.y + v1.z * v1.z + v1.w * v1.w;
  u16x8 o;
  o[0] = f32_to_bf16_rne(v0.x); o[1] = f32_to_bf16_rne(v0.y);
  o[2] = f32_to_bf16_rne(v0.z); o[3] = f32_to_bf16_rne(v0.w);
  o[4] = f32_to_bf16_rne(v1.x); o[5] = f32_to_bf16_rne(v1.y);
  o[6] = f32_to_bf16_rne(v1.z); o[7] = f32_to_bf16_rne(v1.w);
  *(u16x8*)(Xb + (size_t)row * DIM + t * 8) = o;

  #pragma unroll
  for (int off = 32; off > 0; off >>= 1) s += __shfl_down(s, off, 64);
  __shared__ float wsum[4];
  const int lane = t & 63, w = t >> 6;
  if (lane == 0) wsum[w] = s;
  __syncthreads();
  if (t == 0) {
    sq[row] = wsum[0] + wsum[1] + wsum[2] + wsum[3];
    far_bits[row]  = 0u;           // 0.0f
    near_bits[row] = 0x7f800000u;  // +inf
  }
}

// ---------------- 256x256 8-phase pairwise-dist kernel ----------------
// LDS map (bytes):
//   A slots: (db*2+h)*16384              for db,h in {0,1}   [0, 65536)
//   B slots: 65536 + (db*2+h)*16384                          [65536, 131072)
//   sq_r @131072, t_r @132096, sq_c @133120, t_c @134144 ; total 135168
// Each 16 KiB slot = 128 rows x 64 cols bf16, stored as 16 subtiles of
// 16x32 (1024 B); within subtile byte = r'*64 + (c' ^ ((r'>=8)?16:0))*2.
__device__ __forceinline__ void read8(bf16x8 (&f)[4][2], const char* base) {
  #pragma unroll
  for (int m = 0; m < 4; ++m)
    #pragma unroll
    for (int kh = 0; kh < 2; ++kh)
      f[m][kh] = *(const bf16x8*)(base + ((m * 2 + kh) << 10));
}
__device__ __forceinline__ void read4(bf16x8 (&f)[2][2], const char* base) {
  #pragma unroll
  for (int n = 0; n < 2; ++n)
    #pragma unroll
    for (int kh = 0; kh < 2; ++kh)
      f[n][kh] = *(const bf16x8*)(base + ((n * 2 + kh) << 10));
}

template<int MB, int NBq>
__device__ __forceinline__ void do_mfma(f32x4 (&acc)[8][4], bf16x8 (&af)[4][2], bf16x8 (&bf)[2][2]) {
  __builtin_amdgcn_s_setprio(1);
  #pragma unroll
  for (int m = 0; m < 4; ++m)
    #pragma unroll
    for (int n = 0; n < 2; ++n)
      #pragma unroll
      for (int kh = 0; kh < 2; ++kh)
        acc[MB * 4 + m][NBq * 2 + n] =
            __builtin_amdgcn_mfma_f32_16x16x32_bf16(af[m][kh], bf[n][kh],
                                                    acc[MB * 4 + m][NBq * 2 + n], 0, 0, 0);
  __builtin_amdgcn_s_setprio(0);
}

__global__ __launch_bounds__(512, 2) void pairdist_kernel(
    const unsigned short* __restrict__ Xb, const float* __restrict__ sq,
    const int* __restrict__ tgt, unsigned* __restrict__ far_bits,
    unsigned* __restrict__ near_bits) {
  __shared__ __align__(16) char sm[135168];

  const int tid  = threadIdx.x;
  const int lane = tid & 63;
  const int w    = tid >> 6;        // 0..7
  const int wr   = w >> 2;          // 0..1  (M)
  const int wcn  = w & 3;           // 0..3  (N)
  const int fr   = lane & 15;
  const int hi4  = lane >> 4;
  const int i0   = blockIdx.y * 256;
  const int j0   = blockIdx.x * 256;

  float* sq_r = (float*)(sm + 131072);
  int*   t_r  = (int*)  (sm + 132096);
  float* sq_c = (float*)(sm + 133120);
  int*   t_c  = (int*)  (sm + 134144);
  if (tid < 256) { sq_r[tid] = sq[i0 + tid]; t_r[tid] = tgt[i0 + tid]; }
  else { int c = tid - 256; sq_c[c] = sq[j0 + c]; t_c[c] = tgt[j0 + c]; }

  // ds_read per-lane byte offset within a subtile (swizzled)
  const int ard = fr * 64 + ((hi4 * 16) ^ ((lane & 8) << 2));
  const char* smA = sm + wr * 16384 + ard;                                  // +db*32768, +(m*2+kh)*1024
  const char* smB = sm + 65536 + (wcn >> 1) * 16384 + (wcn & 1) * 8192 + ard;

  // staging: per instr a wave covers one 1024-B subtile; lane l -> r'=l>>2,
  // global col pre-swizzled so linear LDS dest yields the swizzled layout.
  const int srow = lane >> 2;
  const int scol = ((lane & 3) * 8) ^ ((lane & 32) ? 16 : 0);
  const unsigned short* gA_src = Xb + (size_t)(i0 + w * 16 + srow) * DIM + scol;
  const unsigned short* gB_src = Xb + (size_t)(j0 + w * 16 + srow) * DIM + scol;
  const int wq0 = w * 2048, wq1 = w * 2048 + 1024;

#define STG_A(db, h, kt) do { \
    const unsigned short* s_ = gA_src + (size_t)(h) * 128 * DIM + (kt) * 64; \
    load_lds16(s_,      sm + ((db) * 2 + (h)) * 16384 + wq0); \
    load_lds16(s_ + 32, sm + ((db) * 2 + (h)) * 16384 + wq1); } while (0)
#define STG_B(db, h, kt) do { \
    const unsigned short* s_ = gB_src + (size_t)(h) * 128 * DIM + (kt) * 64; \
    load_lds16(s_,      sm + 65536 + ((db) * 2 + (h)) * 16384 + wq0); \
    load_lds16(s_ + 32, sm + 65536 + ((db) * 2 + (h)) * 16384 + wq1); } while (0)

  f32x4 acc[8][4] = {};
  bf16x8 a03f[4][2], a47f[4][2], b01f[2][2], b23f[2][2];

  // prologue: tile0 (db0) fully + B(1)h0, A(1)h0 (db1)
  STG_A(0, 0, 0); STG_A(0, 1, 0); STG_B(0, 0, 0); STG_B(0, 1, 0);
  STG_B(1, 0, 1); STG_A(1, 0, 1);
  asm volatile("s_waitcnt lgkmcnt(0)" ::: "memory");  // sq/t LDS writes
  WAIT_VMCNT4();
  BAR();

  for (int it = 0; it < NT / 2; ++it) {
    const int t = 2 * it;
    // ph1: db0 reads a03+b01; stage B(t+1)h1; mfma m0-3 x n0-1
    read8(a03f, smA);
    read4(b01f, smB);
    STG_B(1, 1, t + 1);
    BAR();
    do_mfma<0, 0>(acc, a03f, b01f);
    BAR();
    // ph2: read b23; stage A(t+1)h1; mfma m0-3 x n2-3
    read4(b23f, smB + 4096);
    STG_A(1, 1, t + 1);
    BAR();
    do_mfma<0, 1>(acc, a03f, b23f);
    BAR();
    // ph3: read a47; stage B(t+2)h0; mfma m4-7 x n2-3
    read8(a47f, smA + 8192);
    if (t + 2 < NT) STG_B(0, 0, t + 2);
    BAR();
    do_mfma<1, 1>(acc, a47f, b23f);
    BAR();
    // ph4: stage A(t+2)h0; vmcnt(4); mfma m4-7 x n0-1
    if (t + 2 < NT) STG_A(0, 0, t + 2);
    WAIT_VMCNT4();
    BAR();
    do_mfma<1, 0>(acc, a47f, b01f);
    BAR();
    // ph5: db1 reads a03+b01; stage B(t+2)h1; mfma m0-3 x n0-1
    read8(a03f, smA + 32768);
    read4(b01f, smB + 32768);
    if (t + 2 < NT) STG_B(0, 1, t + 2);
    BAR();
    do_mfma<0, 0>(acc, a03f, b01f);
    BAR();
    // ph6: read b23; stage A(t+2)h1; mfma m0-3 x n2-3
    read4(b23f, smB + 32768 + 4096);
    if (t + 2 < NT) STG_A(0, 1, t + 2);
    BAR();
    do_mfma<0, 1>(acc, a03f, b23f);
    BAR();
    // ph7: read a47; stage B(t+3)h0; mfma m4-7 x n2-3
    read8(a47f, smA + 32768 + 8192);
    if (t + 3 < NT) STG_B(1, 0, t + 3);
    BAR();
    do_mfma<1, 1>(acc, a47f, b23f);
    BAR();
    // ph8: stage A(t+3)h0; vmcnt(4); mfma m4-7 x n0-1
    if (t + 3 < NT) STG_A(1, 0, t + 3);
    WAIT_VMCNT4();
    BAR();
    do_mfma<1, 0>(acc, a47f, b01f);
    BAR();
  }
#undef STG_A
#undef STG_B

  // ---- epilogue: d^2, masked row-side far/near, sqrt after reduce ----
  const float INF = __builtin_inff();
  #pragma unroll
  for (int m = 0; m < 8; ++m) {
    #pragma unroll
    for (int r = 0; r < 4; ++r) {
      const int rl = wr * 128 + m * 16 + hi4 * 4 + r;
      const int gi = i0 + rl;
      const float sqr = sq_r[rl];
      const int   trw = t_r[rl];
      float fmx = 0.0f;
      float nmn = INF;
      #pragma unroll
      for (int n = 0; n < 4; ++n) {
        const int cl = wcn * 64 + n * 16 + fr;
        const float d2 = fmaf(-2.0f, acc[m][n][r], sqr + sq_c[cl]);
        if (trw == t_c[cl]) {
          fmx = fmaxf(fmx, d2);
          if (gi != j0 + cl) nmn = fminf(nmn, d2);
        }
      }
      #pragma unroll
      for (int s = 1; s < 16; s <<= 1) {
        fmx = fmaxf(fmx, __shfl_xor(fmx, s, 64));
        nmn = fminf(nmn, __shfl_xor(nmn, s, 64));
      }
      if (fr == 0) {
        atomicMax(&far_bits[gi],  __float_as_uint(sqrtf(fmaxf(fmx, 1e-12f))));
        atomicMin(&near_bits[gi], __float_as_uint(sqrtf(fmaxf(nmn, 1e-12f))));
      }
    }
  }
}

// ---------------- final deterministic reduction ----------------
__global__ __launch_bounds__(256) void finalize_kernel(
    const unsigned* __restrict__ far_bits, const unsigned* __restrict__ near_bits,
    float* __restrict__ out) {
  __shared__ float red[256];
  const int t = threadIdx.x;
  float s = 0.0f;
  for (int i = t; i < N_PTS; i += 256) {
    float fa = __uint_as_float(far_bits[i]);
    float ne = __uint_as_float(near_bits[i]);
    s += fmaxf(fa - ne, 0.0f);   // near=+inf -> -inf -> 0
  }
  red[t] = s;
  __syncthreads();
  for (int off = 128; off > 0; off >>= 1) {
    if (t < off) red[t] += red[t + off];
    __syncthreads();
  }
  if (t == 0) out[0] = red[0] / (float)N_PTS;
}

extern "C" void kernel_launch(void* const* d_in, const int* in_sizes, int n_in,
                              void* d_out, int out_size, void* d_ws, size_t ws_size,
                              hipStream_t stream) {
  const float* X   = (const float*)d_in[0];
  const int*   tgt = (const int*)d_in[1];
  float*       out = (float*)d_out;

  char* ws = (char*)d_ws;
  unsigned short* Xb = (unsigned short*)ws;                       // 16 MiB
  float*    sq     = (float*)(ws + (size_t)N_PTS * DIM * 2);      // 16 KiB
  unsigned* far_b  = (unsigned*)(ws + (size_t)N_PTS * DIM * 2 + N_PTS * 4);
  unsigned* near_b = (unsigned*)(ws + (size_t)N_PTS * DIM * 2 + N_PTS * 8);

  prep_kernel<<<N_PTS, 256, 0, stream>>>(X, Xb, sq, far_b, near_b);
  dim3 grid(NBT, NBT);
  pairdist_kernel<<<grid, 512, 0, stream>>>(Xb, sq, tgt, far_b, near_b);
  finalize_kernel<<<1, 256, 0, stream>>>(far_b, near_b, out);
}

// Round 5
// 65.310 us; speedup vs baseline: 1.3419x; 1.3416x over previous
//
#include <hip/hip_runtime.h>
#include <hip/hip_bf16.h>
#include <cstdint>
#include <cstddef>

#define N_PTS 4096
#define DIM   2048
#define NCLS  64

typedef __bf16 bf16x8 __attribute__((ext_vector_type(8)));
typedef float  f32x4  __attribute__((ext_vector_type(4)));
typedef unsigned short u16x8 __attribute__((ext_vector_type(8)));

__device__ __forceinline__ unsigned short f32_to_bf16_rne(float f) {
  unsigned u = __float_as_uint(f);
  u += 0x7fffu + ((u >> 16) & 1u);
  return (unsigned short)(u >> 16);
}
__device__ __forceinline__ int imin(int a, int b) { return a < b ? a : b; }

// ---------------- prep: fp32 -> bf16 + exact fp32 row sum-of-squares + init far/near ---
__global__ __launch_bounds__(256) void prep_kernel(const float* __restrict__ X,
                                                   unsigned short* __restrict__ Xb,
                                                   float* __restrict__ sq,
                                                   unsigned* __restrict__ far_bits,
                                                   unsigned* __restrict__ near_bits) {
  const int row = blockIdx.x;
  const int t = threadIdx.x;
  const float4* xr = (const float4*)(X + (size_t)row * DIM);
  float4 v0 = xr[t * 2 + 0];
  float4 v1 = xr[t * 2 + 1];
  float s = v0.x * v0.x + v0.y * v0.y + v0.z * v0.z + v0.w * v0.w
          + v1.x * v1.x + v1.y * v1.y + v1.z * v1.z + v1.w * v1.w;
  u16x8 o;
  o[0] = f32_to_bf16_rne(v0.x); o[1] = f32_to_bf16_rne(v0.y);
  o[2] = f32_to_bf16_rne(v0.z); o[3] = f32_to_bf16_rne(v0.w);
  o[4] = f32_to_bf16_rne(v1.x); o[5] = f32_to_bf16_rne(v1.y);
  o[6] = f32_to_bf16_rne(v1.z); o[7] = f32_to_bf16_rne(v1.w);
  *(u16x8*)(Xb + (size_t)row * DIM + t * 8) = o;

  #pragma unroll
  for (int off = 32; off > 0; off >>= 1) s += __shfl_down(s, off, 64);
  __shared__ float wsum[4];
  const int lane = t & 63, w = t >> 6;
  if (lane == 0) wsum[w] = s;
  __syncthreads();
  if (t == 0) {
    sq[row] = wsum[0] + wsum[1] + wsum[2] + wsum[3];
    far_bits[row]  = 0u;           // 0.0f
    near_bits[row] = 0x7f800000u;  // +inf
  }
}

// ---------------- bucket: class histogram + prefix + scatter ----------------
// 1 block, 1024 threads = 16 waves. Wave-private histograms -> no hot atomics.
// perm order within a class is atomic-order-dependent, but downstream far/near
// are commutative min/max over the same multiset -> final output deterministic.
__global__ __launch_bounds__(1024) void bucket_kernel(const int* __restrict__ tgt,
                                                      int* __restrict__ perm,
                                                      int* __restrict__ cbase,
                                                      int* __restrict__ ccnt) {
  __shared__ int hist[16][NCLS];
  __shared__ int woff[16][NCLS];
  __shared__ int cbs[NCLS];
  const int tid = threadIdx.x;
  const int w = tid >> 6, l = tid & 63;
  hist[w][l] = 0;
  __syncthreads();
  int cls[4];
  #pragma unroll
  for (int r = 0; r < 4; ++r) {
    cls[r] = tgt[w * 256 + r * 64 + l];
    atomicAdd(&hist[w][cls[r]], 1);
  }
  __syncthreads();
  if (tid < NCLS) {
    int run = 0;
    for (int ww = 0; ww < 16; ++ww) { woff[ww][tid] = run; run += hist[ww][tid]; }
    ccnt[tid] = run;
    cbs[tid] = run;
  }
  __syncthreads();
  if (tid == 0) {
    int run = 0;
    for (int c = 0; c < NCLS; ++c) { int t2 = cbs[c]; cbs[c] = run; run += t2; }
  }
  __syncthreads();
  if (tid < NCLS) {
    cbase[tid] = cbs[tid];
    for (int ww = 0; ww < 16; ++ww) woff[ww][tid] += cbs[tid];
  }
  __syncthreads();
  #pragma unroll
  for (int r = 0; r < 4; ++r) {
    int pos = atomicAdd(&woff[w][cls[r]], 1);
    perm[pos] = w * 256 + r * 64 + l;
  }
}

// ---------------- per-class pairwise distances (only same-class pairs matter) ------
// grid = NCLS*4 blocks (class c = bid>>2, quadrant slot q = bid&3), 256 thr = 4 waves.
// Class tile padded to T*64 (T = ceil(n/64), <=4); pad indices clamp to a real
// member -> duplicate pairs are idempotent for atomicMax/Min, and self/dup pairs
// are excluded from `near` by the gi!=gj guard.
// Per wave: 16-row x 64-col stripe, full K. MFMA fragments are gathered directly
// from global into registers (per-lane 16B load == exact 16x16x32 frag layout).
__global__ __launch_bounds__(256) void cls_pairdist_kernel(
    const unsigned short* __restrict__ Xb, const float* __restrict__ sq,
    const int* __restrict__ perm, const int* __restrict__ cbase,
    const int* __restrict__ ccnt,
    unsigned* __restrict__ far_bits, unsigned* __restrict__ near_bits) {
  const int c = blockIdx.x >> 2, q = blockIdx.x & 3;
  const int n = ccnt[c];
  if (n <= 0) return;
  int T = (n + 63) >> 6; if (T > 4) T = 4;
  if (q >= T * T) return;
  const int base = cbase[c];

  __shared__ int   idx_s[256];
  __shared__ float sq_s[256];
  {
    int j = threadIdx.x;
    int id = perm[base + imin(j, n - 1)];
    idx_s[j] = id;
    sq_s[j] = sq[id];
  }
  __syncthreads();

  const int lane = threadIdx.x & 63, wv = threadIdx.x >> 6;
  const int fr = lane & 15, hi4 = lane >> 4;
  const float INF = __builtin_inff();

  for (int s = q; s < T * T; s += 4) {
    const int rt = s / T, ct = s - rt * T;
    const int rbase = rt * 64 + wv * 16;   // <= 240
    const int cb = ct * 64;                // <= 192

    const int ra = idx_s[rbase + fr];
    const unsigned short* ap = Xb + (size_t)ra * DIM + hi4 * 8;

    const unsigned short* bp[4];
    int gj[4]; float sqB[4];
    #pragma unroll
    for (int nj = 0; nj < 4; ++nj) {
      int cj = cb + nj * 16 + fr;
      int rbj = idx_s[cj];
      gj[nj] = rbj; sqB[nj] = sq_s[cj];
      bp[nj] = Xb + (size_t)rbj * DIM + hi4 * 8;
    }

    f32x4 acc[4] = {};
    #pragma unroll 2
    for (int kt = 0; kt < DIM / 64; ++kt) {
      const int k0 = kt * 64;
      bf16x8 av0 = *(const bf16x8*)(ap + k0);
      bf16x8 av1 = *(const bf16x8*)(ap + k0 + 32);
      #pragma unroll
      for (int nj = 0; nj < 4; ++nj) {
        bf16x8 bv0 = *(const bf16x8*)(bp[nj] + k0);
        bf16x8 bv1 = *(const bf16x8*)(bp[nj] + k0 + 32);
        acc[nj] = __builtin_amdgcn_mfma_f32_16x16x32_bf16(av0, bv0, acc[nj], 0, 0, 0);
        acc[nj] = __builtin_amdgcn_mfma_f32_16x16x32_bf16(av1, bv1, acc[nj], 0, 0, 0);
      }
    }

    // epilogue: d^2 (reduce, sqrt once), row-side far/near via shfl + atomics
    #pragma unroll
    for (int rr = 0; rr < 4; ++rr) {
      const int rl = rbase + hi4 * 4 + rr;
      const int gi = idx_s[rl];
      const float sqr = sq_s[rl];
      float fmx = 0.0f, nmn = INF;
      #pragma unroll
      for (int nj = 0; nj < 4; ++nj) {
        const float d2 = fmaf(-2.0f, acc[nj][rr], sqr + sqB[nj]);
        fmx = fmaxf(fmx, d2);
        if (gi != gj[nj]) nmn = fminf(nmn, d2);
      }
      #pragma unroll
      for (int sh = 1; sh < 16; sh <<= 1) {
        fmx = fmaxf(fmx, __shfl_xor(fmx, sh, 64));
        nmn = fminf(nmn, __shfl_xor(nmn, sh, 64));
      }
      if (fr == 0) {
        atomicMax(&far_bits[gi],  __float_as_uint(sqrtf(fmaxf(fmx, 1e-12f))));
        atomicMin(&near_bits[gi], __float_as_uint(sqrtf(fmaxf(nmn, 1e-12f))));
      }
    }
  }
}

// ---------------- final deterministic reduction ----------------
__global__ __launch_bounds__(256) void finalize_kernel(
    const unsigned* __restrict__ far_bits, const unsigned* __restrict__ near_bits,
    float* __restrict__ out) {
  __shared__ float red[256];
  const int t = threadIdx.x;
  float s = 0.0f;
  for (int i = t; i < N_PTS; i += 256) {
    float fa = __uint_as_float(far_bits[i]);
    float ne = __uint_as_float(near_bits[i]);
    s += fmaxf(fa - ne, 0.0f);   // near=+inf -> -inf -> 0
  }
  red[t] = s;
  __syncthreads();
  for (int off = 128; off > 0; off >>= 1) {
    if (t < off) red[t] += red[t + off];
    __syncthreads();
  }
  if (t == 0) out[0] = red[0] / (float)N_PTS;
}

extern "C" void kernel_launch(void* const* d_in, const int* in_sizes, int n_in,
                              void* d_out, int out_size, void* d_ws, size_t ws_size,
                              hipStream_t stream) {
  const float* X   = (const float*)d_in[0];
  const int*   tgt = (const int*)d_in[1];
  float*       out = (float*)d_out;

  char* ws = (char*)d_ws;
  const size_t XB_BYTES = (size_t)N_PTS * DIM * 2;   // 16 MiB
  unsigned short* Xb = (unsigned short*)ws;
  float*    sq     = (float*)(ws + XB_BYTES);
  unsigned* far_b  = (unsigned*)(ws + XB_BYTES + N_PTS * 4);
  unsigned* near_b = (unsigned*)(ws + XB_BYTES + N_PTS * 8);
  int*      perm   = (int*)(ws + XB_BYTES + N_PTS * 12);
  int*      cbs    = (int*)(ws + XB_BYTES + N_PTS * 16);
  int*      ccn    = (int*)(ws + XB_BYTES + N_PTS * 16 + 256);

  prep_kernel<<<N_PTS, 256, 0, stream>>>(X, Xb, sq, far_b, near_b);
  bucket_kernel<<<1, 1024, 0, stream>>>(tgt, perm, cbs, ccn);
  cls_pairdist_kernel<<<NCLS * 4, 256, 0, stream>>>(Xb, sq, perm, cbs, ccn, far_b, near_b);
  finalize_kernel<<<1, 256, 0, stream>>>(far_b, near_b, out);
}

// Round 6
// 46.966 us; speedup vs baseline: 1.8660x; 1.3906x over previous
//
#include <hip/hip_runtime.h>
#include <hip/hip_bf16.h>
#include <cstdint>
#include <cstddef>

#define N_PTS 4096
#define DIM   2048
#define NCLS  64
#define GSTRIDE 68                      // floats; 68*4=272 B, 16-B multiple
#define GSLOT   (64 * GSTRIDE * 4)      // 17408 B per wave slot
#define IDX_OFF (8 * GSLOT)             // 139264
#define SQ_OFF  (IDX_OFF + 2048)        // 141312 ; total 143360 <= 160 KiB

typedef __bf16 bf16x8 __attribute__((ext_vector_type(8)));
typedef float  f32x4  __attribute__((ext_vector_type(4)));
typedef unsigned short u16x8 __attribute__((ext_vector_type(8)));

__device__ __forceinline__ unsigned short f32_to_bf16_rne(float f) {
  unsigned u = __float_as_uint(f);
  u += 0x7fffu + ((u >> 16) & 1u);
  return (unsigned short)(u >> 16);
}
__device__ __forceinline__ int imin(int a, int b) { return a < b ? a : b; }

// ---------------- prep: fp32 -> bf16 + exact fp32 row sum-of-squares + init far/near ---
__global__ __launch_bounds__(256) void prep_kernel(const float* __restrict__ X,
                                                   unsigned short* __restrict__ Xb,
                                                   float* __restrict__ sq,
                                                   unsigned* __restrict__ far_bits,
                                                   unsigned* __restrict__ near_bits) {
  const int row = blockIdx.x;
  const int t = threadIdx.x;
  const float4* xr = (const float4*)(X + (size_t)row * DIM);
  float4 v0 = xr[t * 2 + 0];
  float4 v1 = xr[t * 2 + 1];
  float s = v0.x * v0.x + v0.y * v0.y + v0.z * v0.z + v0.w * v0.w
          + v1.x * v1.x + v1.y * v1.y + v1.z * v1.z + v1.w * v1.w;
  u16x8 o;
  o[0] = f32_to_bf16_rne(v0.x); o[1] = f32_to_bf16_rne(v0.y);
  o[2] = f32_to_bf16_rne(v0.z); o[3] = f32_to_bf16_rne(v0.w);
  o[4] = f32_to_bf16_rne(v1.x); o[5] = f32_to_bf16_rne(v1.y);
  o[6] = f32_to_bf16_rne(v1.z); o[7] = f32_to_bf16_rne(v1.w);
  *(u16x8*)(Xb + (size_t)row * DIM + t * 8) = o;

  #pragma unroll
  for (int off = 32; off > 0; off >>= 1) s += __shfl_down(s, off, 64);
  __shared__ float wsum[4];
  const int lane = t & 63, w = t >> 6;
  if (lane == 0) wsum[w] = s;
  __syncthreads();
  if (t == 0) {
    sq[row] = wsum[0] + wsum[1] + wsum[2] + wsum[3];
    far_bits[row]  = 0u;           // 0.0f
    near_bits[row] = 0x7f800000u;  // +inf
  }
}

// ---------------- bucket: class histogram + prefix + scatter ----------------
__global__ __launch_bounds__(1024) void bucket_kernel(const int* __restrict__ tgt,
                                                      int* __restrict__ perm,
                                                      int* __restrict__ cbase,
                                                      int* __restrict__ ccnt) {
  __shared__ int hist[16][NCLS];
  __shared__ int woff[16][NCLS];
  __shared__ int cbs[NCLS];
  const int tid = threadIdx.x;
  const int w = tid >> 6, l = tid & 63;
  hist[w][l] = 0;
  __syncthreads();
  int cls[4];
  #pragma unroll
  for (int r = 0; r < 4; ++r) {
    cls[r] = tgt[w * 256 + r * 64 + l];
    atomicAdd(&hist[w][cls[r]], 1);
  }
  __syncthreads();
  if (tid < NCLS) {
    int run = 0;
    for (int ww = 0; ww < 16; ++ww) { woff[ww][tid] = run; run += hist[ww][tid]; }
    ccnt[tid] = run;
    cbs[tid] = run;
  }
  __syncthreads();
  if (tid == 0) {
    int run = 0;
    for (int c = 0; c < NCLS; ++c) { int t2 = cbs[c]; cbs[c] = run; run += t2; }
  }
  __syncthreads();
  if (tid < NCLS) {
    cbase[tid] = cbs[tid];
    for (int ww = 0; ww < 16; ++ww) woff[ww][tid] += cbs[tid];
  }
  __syncthreads();
  #pragma unroll
  for (int r = 0; r < 4; ++r) {
    int pos = atomicAdd(&woff[w][cls[r]], 1);
    perm[pos] = w * 256 + r * 64 + l;
  }
}

// ---------------- per-class pairwise distances, 8-way K-split per 64x64 unit ------
// grid = NCLS*4 (class c = bid>>2, unit slot q = bid&3), 512 thr = 8 waves.
// Each wave computes a PARTIAL Gram of the unit over its 256-K chunk (4 k-tiles),
// fragments gathered directly from global (L2/L3-resident). 8 partials reduced in
// LDS, then d^2 epilogue with 8-thread/row shfl reduce + idempotent atomics.
// Assumes class size <= 512 (inputs: ~64 expected, binomial tail; idx_s capacity).
__global__ __launch_bounds__(512, 2) void cls_pairdist_kernel(
    const unsigned short* __restrict__ Xb, const float* __restrict__ sq,
    const int* __restrict__ perm, const int* __restrict__ cbase,
    const int* __restrict__ ccnt,
    unsigned* __restrict__ far_bits, unsigned* __restrict__ near_bits) {
  const int c = blockIdx.x >> 2, q = blockIdx.x & 3;
  const int n = ccnt[c];
  if (n <= 0) return;
  int T = (n + 63) >> 6; if (T > 8) T = 8;
  if (q >= T * T) return;
  const int base = cbase[c];
  const int P = T * 64;

  __shared__ __align__(16) char sm[SQ_OFF + 2048];
  int*   idx_s = (int*)(sm + IDX_OFF);
  float* sq_s  = (float*)(sm + SQ_OFF);
  for (int j = threadIdx.x; j < P; j += 512) {
    int id = perm[base + imin(j, n - 1)];
    idx_s[j] = id;
    sq_s[j] = sq[id];
  }
  __syncthreads();

  const int tid  = threadIdx.x;
  const int lane = tid & 63, wv = tid >> 6;
  const int fr = lane & 15, hi4 = lane >> 4;
  const int koff = wv * 256 + hi4 * 8;        // this wave's K chunk + frag k-offset
  float* gslot = (float*)(sm + wv * GSLOT);
  const float INF = __builtin_inff();

  for (int s = q; s < T * T; s += 4) {
    const int rt = s / T, ct = s - rt * T;
    const int rbase0 = rt * 64, cbase0 = ct * 64;

    // per-lane row pointers for A (rows) and B (cols) fragments
    const unsigned short* ap[4];
    const unsigned short* bp[4];
    #pragma unroll
    for (int m = 0; m < 4; ++m)
      ap[m] = Xb + (size_t)idx_s[rbase0 + m * 16 + fr] * DIM + koff;
    #pragma unroll
    for (int nn = 0; nn < 4; ++nn)
      bp[nn] = Xb + (size_t)idx_s[cbase0 + nn * 16 + fr] * DIM + koff;

    f32x4 acc[4][4] = {};
    #pragma unroll 2
    for (int kt = 0; kt < 4; ++kt) {
      const int k0 = kt * 64;
      bf16x8 av[4][2], bv[4][2];
      #pragma unroll
      for (int m = 0; m < 4; ++m) {
        av[m][0] = *(const bf16x8*)(ap[m] + k0);
        av[m][1] = *(const bf16x8*)(ap[m] + k0 + 32);
      }
      #pragma unroll
      for (int nn = 0; nn < 4; ++nn) {
        bv[nn][0] = *(const bf16x8*)(bp[nn] + k0);
        bv[nn][1] = *(const bf16x8*)(bp[nn] + k0 + 32);
      }
      #pragma unroll
      for (int m = 0; m < 4; ++m)
        #pragma unroll
        for (int nn = 0; nn < 4; ++nn) {
          acc[m][nn] = __builtin_amdgcn_mfma_f32_16x16x32_bf16(av[m][0], bv[nn][0], acc[m][nn], 0, 0, 0);
          acc[m][nn] = __builtin_amdgcn_mfma_f32_16x16x32_bf16(av[m][1], bv[nn][1], acc[m][nn], 0, 0, 0);
        }
    }

    // write partial Gram to this wave's LDS slot (row = m*16+hi4*4+r, col = n*16+fr)
    #pragma unroll
    for (int m = 0; m < 4; ++m)
      #pragma unroll
      for (int nn = 0; nn < 4; ++nn)
        #pragma unroll
        for (int r = 0; r < 4; ++r)
          gslot[(m * 16 + hi4 * 4 + r) * GSTRIDE + nn * 16 + fr] = acc[m][nn][r];
    __syncthreads();

    // reduce 8 partials + epilogue: thread owns row (tid>>3), cols (tid&7)*8..+8
    const int rrow = tid >> 3;
    const int cch = (tid & 7) * 8;
    f32x4 ga = {}, gb = {};
    #pragma unroll
    for (int w2 = 0; w2 < 8; ++w2) {
      const char* gb_ = sm + w2 * GSLOT + (size_t)rrow * (GSTRIDE * 4) + cch * 4;
      ga += *(const f32x4*)(gb_);
      gb += *(const f32x4*)(gb_ + 16);
    }
    const int gi = idx_s[rbase0 + rrow];
    const float sqr = sq_s[rbase0 + rrow];
    float fmx = 0.0f, nmn = INF;
    #pragma unroll
    for (int i = 0; i < 8; ++i) {
      const int col = cch + i;
      const float g = (i < 4) ? ga[i] : gb[i - 4];
      const float d2 = fmaf(-2.0f, g, sqr + sq_s[cbase0 + col]);
      fmx = fmaxf(fmx, d2);
      if (gi != idx_s[cbase0 + col]) nmn = fminf(nmn, d2);
    }
    #pragma unroll
    for (int sh = 1; sh < 8; sh <<= 1) {
      fmx = fmaxf(fmx, __shfl_xor(fmx, sh, 64));
      nmn = fminf(nmn, __shfl_xor(nmn, sh, 64));
    }
    if ((tid & 7) == 0) {
      atomicMax(&far_bits[gi],  __float_as_uint(sqrtf(fmaxf(fmx, 1e-12f))));
      atomicMin(&near_bits[gi], __float_as_uint(sqrtf(fmaxf(nmn, 1e-12f))));
    }
    __syncthreads();   // protect slots before next unit overwrites
  }
}

// ---------------- final deterministic reduction ----------------
__global__ __launch_bounds__(256) void finalize_kernel(
    const unsigned* __restrict__ far_bits, const unsigned* __restrict__ near_bits,
    float* __restrict__ out) {
  __shared__ float red[256];
  const int t = threadIdx.x;
  float s = 0.0f;
  for (int i = t; i < N_PTS; i += 256) {
    float fa = __uint_as_float(far_bits[i]);
    float ne = __uint_as_float(near_bits[i]);
    s += fmaxf(fa - ne, 0.0f);   // near=+inf -> -inf -> 0
  }
  red[t] = s;
  __syncthreads();
  for (int off = 128; off > 0; off >>= 1) {
    if (t < off) red[t] += red[t + off];
    __syncthreads();
  }
  if (t == 0) out[0] = red[0] / (float)N_PTS;
}

extern "C" void kernel_launch(void* const* d_in, const int* in_sizes, int n_in,
                              void* d_out, int out_size, void* d_ws, size_t ws_size,
                              hipStream_t stream) {
  const float* X   = (const float*)d_in[0];
  const int*   tgt = (const int*)d_in[1];
  float*       out = (float*)d_out;

  char* ws = (char*)d_ws;
  const size_t XB_BYTES = (size_t)N_PTS * DIM * 2;   // 16 MiB
  unsigned short* Xb = (unsigned short*)ws;
  float*    sq     = (float*)(ws + XB_BYTES);
  unsigned* far_b  = (unsigned*)(ws + XB_BYTES + N_PTS * 4);
  unsigned* near_b = (unsigned*)(ws + XB_BYTES + N_PTS * 8);
  int*      perm   = (int*)(ws + XB_BYTES + N_PTS * 12);
  int*      cbs    = (int*)(ws + XB_BYTES + N_PTS * 16);
  int*      ccn    = (int*)(ws + XB_BYTES + N_PTS * 16 + 256);

  prep_kernel<<<N_PTS, 256, 0, stream>>>(X, Xb, sq, far_b, near_b);
  bucket_kernel<<<1, 1024, 0, stream>>>(tgt, perm, cbs, ccn);
  cls_pairdist_kernel<<<NCLS * 4, 512, 0, stream>>>(Xb, sq, perm, cbs, ccn, far_b, near_b);
  finalize_kernel<<<1, 256, 0, stream>>>(far_b, near_b, out);
}